// Round 3
// baseline (28.496 us; speedup 1.0000x reference)
//
#include <hip/hip_runtime.h>

// Output = Re(O @ H), shape [B,2,2] -> 4 floats/elem:
// [Re H10, Re H11, Re H00, Re H01] = [k*cos(2psi), h11, h00, k*cos(2psi)]
// where k=(d2-d1)*cos(th)*sin(th), h00=d1*c^2+d2*s^2, h11=d1*s^2+d2*c^2,
// d1=2*x1, d2=2*x2*(1-|x1|). delta (U[:,2]) and all imaginary parts of the
// diagonal phases cancel in the real part of H's off-diagonals only via
// cos(2psi); psi = U[:,0].
__global__ void __launch_bounds__(256) vo_kernel(
    const float* __restrict__ U,
    const float* __restrict__ x1,
    const float* __restrict__ x2,
    float* __restrict__ out,
    int n,
    long long out_floats)
{
    int stride = gridDim.x * blockDim.x;
    for (int i = blockIdx.x * blockDim.x + threadIdx.x; i < n; i += stride) {
        float u0 = U[3 * i + 0];   // psi
        float th = U[3 * i + 1];   // theta
        // U[3*i+2] (delta) cancels in H = U d U^H.
        float l1 = x1[i];
        float l2 = x2[i] * (1.0f - fabsf(l1));
        float d1 = 2.0f * l1;
        float d2 = 2.0f * l2;

        float st = __sinf(th);
        float ct = __cosf(th);
        float c2 = __cosf(2.0f * u0);

        float k   = (d2 - d1) * ct * st;
        float h00 = d1 * ct * ct + d2 * st * st;
        float h11 = d1 * st * st + d2 * ct * ct;
        float kr  = k * c2;

        long long base = 4LL * (long long)i;
        if (base + 4 <= out_floats) {
            *reinterpret_cast<float4*>(out + base) = make_float4(kr, h11, h00, kr);
        } else {
            float vals[4] = {kr, h11, h00, kr};
            for (int j = 0; j < 4; ++j)
                if (base + j < out_floats) out[base + j] = vals[j];
        }
    }
}

extern "C" void kernel_launch(void* const* d_in, const int* in_sizes, int n_in,
                              void* d_out, int out_size, void* d_ws, size_t ws_size,
                              hipStream_t stream) {
    const float* U  = (const float*)d_in[0];
    const float* x1 = (const float*)d_in[1];
    const float* x2 = (const float*)d_in[2];
    // d_in[3] is O (constant swap matrix) — folded into the kernel.
    float* out = (float*)d_out;

    int n = in_sizes[1];                         // x1 count == B_SIZE
    long long out_floats = (long long)out_size;  // floats writable in d_out

    int block = 256;
    int grid = (n + block - 1) / block;
    if (grid > 2048) grid = 2048;                // grid-stride
    vo_kernel<<<grid, block, 0, stream>>>(U, x1, x2, out, n, out_floats);
}